// Round 4
// baseline (1290.519 us; speedup 1.0000x reference)
//
#include <hip/hip_runtime.h>
#include <hip/hip_bf16.h>
#include <cstdint>
#include <cstddef>

#define Bn 64
#define Tn 50
#define Pn 49
#define En 512
#define Hn 512
#define Vn 10000
#define IEn 1024
#define G5 2560   // 5*H
#define NBLK 64   // persistent scan blocks (<= #CUs, 1/CU by LDS => co-resident)

typedef __attribute__((ext_vector_type(8))) short bf16x8;
typedef __attribute__((ext_vector_type(4))) float f32x4;

__device__ __forceinline__ float sigm(float x)  { return 1.0f / (1.0f + __expf(-x)); }
__device__ __forceinline__ float tanh_f(float x){ return 1.0f - 2.0f / (1.0f + __expf(2.0f * x)); }

__device__ __forceinline__ unsigned short f2b(float f) {
    union { float f; unsigned int u; } c; c.f = f;
    unsigned int u = c.u;
    u += 0x7fffu + ((u >> 16) & 1u);   // RNE (finite values only)
    return (unsigned short)(u >> 16);
}
__device__ __forceinline__ float b2f(unsigned short u) {
    union { unsigned int u; float f; } c; c.u = ((unsigned int)u) << 16;
    return c.f;
}

// ---------------------------------------------------------------------------
// fp32 tiled GEMM (small ops only): C[M,N] = A[M,K] @ B[K,N] (+bias)
// ---------------------------------------------------------------------------
template<bool GATHER>
__global__ __launch_bounds__(256)
void gemm64(const float* __restrict__ A, int lda,
            const float* __restrict__ B,
            float* __restrict__ C,
            int M, int N, int K,
            const float* __restrict__ bias,
            const float* __restrict__ rowadd, int rowDiv, long rowStride,
            const int* __restrict__ gidx)
{
    const int n0 = blockIdx.x * 64;
    const int m0 = blockIdx.y * 64;
    const long koff = (long)blockIdx.z * K;
    const float* Bp = B + koff * N;
    float* Cp = C + (gridDim.z > 1 ? (size_t)blockIdx.z * (size_t)M * (size_t)N : (size_t)0);

    __shared__ float As[16][64];
    __shared__ float Bs[16][64];

    const int tid = threadIdx.x;
    const int tx = tid & 15;
    const int ty = tid >> 4;
    const int ra = tid >> 2;
    const int ca = (tid & 3) << 2;

    long arow = GATHER ? (long)gidx[m0 + ra] : (long)(m0 + ra);
    const float* Arow = A + arow * (long)lda + koff + ca;

    const int kl = ty;
    const int nb = tx << 2;
    const int ncol = n0 + nb;

    float acc[4][4] = {{0.f,0.f,0.f,0.f},{0.f,0.f,0.f,0.f},{0.f,0.f,0.f,0.f},{0.f,0.f,0.f,0.f}};

    for (int k0 = 0; k0 < K; k0 += 16) {
        float4 av = *(const float4*)(Arow + k0);
        float4 bv;
        const float* bptr = Bp + (long)(k0 + kl) * N + ncol;
        if (ncol + 3 < N) {
            bv = *(const float4*)bptr;
        } else {
            bv.x = (ncol + 0 < N) ? bptr[0] : 0.f;
            bv.y = (ncol + 1 < N) ? bptr[1] : 0.f;
            bv.z = (ncol + 2 < N) ? bptr[2] : 0.f;
            bv.w = (ncol + 3 < N) ? bptr[3] : 0.f;
        }
        __syncthreads();
        As[ca + 0][ra] = av.x; As[ca + 1][ra] = av.y;
        As[ca + 2][ra] = av.z; As[ca + 3][ra] = av.w;
        *(float4*)&Bs[kl][nb] = bv;
        __syncthreads();
        #pragma unroll
        for (int kk = 0; kk < 16; kk++) {
            const float4 a = *(const float4*)&As[kk][ty << 2];
            const float4 b = *(const float4*)&Bs[kk][tx << 2];
            const float a_[4] = {a.x, a.y, a.z, a.w};
            const float b_[4] = {b.x, b.y, b.z, b.w};
            #pragma unroll
            for (int i = 0; i < 4; i++)
                #pragma unroll
                for (int j = 0; j < 4; j++)
                    acc[i][j] = fmaf(a_[i], b_[j], acc[i][j]);
        }
    }

    #pragma unroll
    for (int i = 0; i < 4; i++) {
        const int rr = m0 + (ty << 2) + i;
        #pragma unroll
        for (int j = 0; j < 4; j++) {
            const int cc = n0 + (tx << 2) + j;
            if (cc < N) {
                float v = acc[i][j];
                if (bias)   v += bias[cc];
                if (rowadd) v += rowadd[(long)(rr / rowDiv) * rowStride + cc];
                Cp[(long)rr * N + cc] = v;
            }
        }
    }
}

// ---------------------------------------------------------------------------
// bf16 MFMA GEMM: C[M,N] = A_bf[M,K] @ BT_bf[N,K]^T, fp32 accum.
// 128x128 tile, BK=32, 4 waves (2x2). GM: A-row gather + C-row scatter via
// ridx[0..*dcnt) (row compaction for masked (b,t) rows).
// ---------------------------------------------------------------------------
template<int OUTF, int OUTB, int GM>
__global__ __launch_bounds__(256)
void gemm_mfma(const unsigned short* __restrict__ A,
               const unsigned short* __restrict__ BT,
               float* __restrict__ Cf, unsigned short* __restrict__ Cb,
               int M, int N, int K,
               const float* __restrict__ bias,
               const float* __restrict__ rowadd, int rowDiv,
               const int* __restrict__ ridx, const int* __restrict__ dcnt)
{
    __shared__ __align__(16) unsigned short Asm[128][40];
    __shared__ __align__(16) unsigned short Bsm[128][40];

    int Meff = M;
    if (GM) Meff = *dcnt;
    const int m0 = blockIdx.y * 128;
    if (GM && m0 >= Meff) return;
    const int n0 = blockIdx.x * 128;

    const int tid = threadIdx.x;
    const int lane = tid & 63;
    const int wid = tid >> 6;
    const int wm = wid >> 1;
    const int wn = wid & 1;

    const int r0 = tid >> 2;      // staging row (and +64)
    const int kg = tid & 3;       // staging k-group of 8 bf16

    const int ar0 = m0 + r0, ar1 = m0 + r0 + 64;
    const int br0 = n0 + r0, br1 = n0 + r0 + 64;
    long arow0, arow1;
    if (GM) {
        arow0 = (ar0 < Meff) ? (long)ridx[ar0] : 0;
        arow1 = (ar1 < Meff) ? (long)ridx[ar1] : 0;
    } else {
        arow0 = ar0; arow1 = ar1;
    }

    f32x4 acc[4][4] = {};
    const uint4 zero4 = {0u, 0u, 0u, 0u};

    uint4 a0, a1, b0, b1;
    {
        const long ka = (long)kg * 8;
        a0 = (GM || ar0 < Meff) ? *(const uint4*)(A + arow0 * K + ka) : zero4;
        a1 = (GM || ar1 < Meff) ? *(const uint4*)(A + arow1 * K + ka) : zero4;
        b0 = (br0 < N) ? *(const uint4*)(BT + (long)br0 * K + ka) : zero4;
        b1 = (br1 < N) ? *(const uint4*)(BT + (long)br1 * K + ka) : zero4;
    }

    for (int k0 = 0; k0 < K; k0 += 32) {
        __syncthreads();
        *(uint4*)&Asm[r0     ][kg * 8] = a0;
        *(uint4*)&Asm[r0 + 64][kg * 8] = a1;
        *(uint4*)&Bsm[r0     ][kg * 8] = b0;
        *(uint4*)&Bsm[r0 + 64][kg * 8] = b1;
        __syncthreads();

        if (k0 + 32 < K) {
            const long ka = (long)(k0 + 32) + kg * 8;
            a0 = (GM || ar0 < Meff) ? *(const uint4*)(A + arow0 * K + ka) : zero4;
            a1 = (GM || ar1 < Meff) ? *(const uint4*)(A + arow1 * K + ka) : zero4;
            b0 = (br0 < N) ? *(const uint4*)(BT + (long)br0 * K + ka) : zero4;
            b1 = (br1 < N) ? *(const uint4*)(BT + (long)br1 * K + ka) : zero4;
        }

        bf16x8 af[4], bfr[4];
        const int arow = wm * 64 + (lane & 15);
        const int brow = wn * 64 + (lane & 15);
        const int kcol = (lane >> 4) * 8;
        #pragma unroll
        for (int i = 0; i < 4; i++) {
            af[i]  = *(const bf16x8*)&Asm[arow + i * 16][kcol];
            bfr[i] = *(const bf16x8*)&Bsm[brow + i * 16][kcol];
        }
        #pragma unroll
        for (int mi = 0; mi < 4; mi++)
            #pragma unroll
            for (int ni = 0; ni < 4; ni++)
                acc[mi][ni] = __builtin_amdgcn_mfma_f32_16x16x32_bf16(af[mi], bfr[ni], acc[mi][ni], 0, 0, 0);
    }

    const int crow = m0 + wm * 64 + (lane >> 4) * 4;
    const int ccol0 = n0 + wn * 64 + (lane & 15);
    #pragma unroll
    for (int ni = 0; ni < 4; ni++) {
        const int col = ccol0 + ni * 16;
        if (col >= N) continue;
        const float bvv = bias ? bias[col] : 0.f;
        #pragma unroll
        for (int mi = 0; mi < 4; mi++) {
            #pragma unroll
            for (int r = 0; r < 4; r++) {
                const int rr = crow + mi * 16 + r;
                if (rr < Meff) {
                    const long orow = GM ? (long)ridx[rr] : (long)rr;
                    float v = acc[mi][ni][r] + bvv;
                    if (rowadd) v += rowadd[(long)(rr / rowDiv) * N + col];
                    if (OUTF) Cf[orow * N + col] = v;
                    if (OUTB) Cb[orow * N + col] = f2b(v);
                }
            }
        }
    }
}

// out[n][k] = bf16(in[k][n])
__global__ __launch_bounds__(256)
void transpose_bf16(const float* __restrict__ in, unsigned short* __restrict__ out,
                    int K, int N, int istride)
{
    __shared__ float tile[32][33];
    const int k0 = blockIdx.y * 32;
    const int n0 = blockIdx.x * 32;
    const int tx = threadIdx.x & 31, ty = threadIdx.x >> 5;
    #pragma unroll
    for (int j = 0; j < 4; j++) {
        int k = k0 + ty + j * 8, n = n0 + tx;
        tile[ty + j * 8][tx] = (k < K && n < N) ? in[(long)k * istride + n] : 0.f;
    }
    __syncthreads();
    #pragma unroll
    for (int j = 0; j < 4; j++) {
        int n = n0 + ty + j * 8, k = k0 + tx;
        if (n < N && k < K) out[(long)n * K + k] = f2b(tile[tx][ty + j * 8]);
    }
}

// hi/lo split transpose: hi = bf16(x), lo = bf16(x - hi)
__global__ __launch_bounds__(256)
void transpose_bf16_hilo(const float* __restrict__ in,
                         unsigned short* __restrict__ hi_o, unsigned short* __restrict__ lo_o,
                         int K, int N, int istride)
{
    __shared__ float tile[32][33];
    const int k0 = blockIdx.y * 32;
    const int n0 = blockIdx.x * 32;
    const int tx = threadIdx.x & 31, ty = threadIdx.x >> 5;
    #pragma unroll
    for (int j = 0; j < 4; j++) {
        int k = k0 + ty + j * 8, n = n0 + tx;
        tile[ty + j * 8][tx] = (k < K && n < N) ? in[(long)k * istride + n] : 0.f;
    }
    __syncthreads();
    #pragma unroll
    for (int j = 0; j < 4; j++) {
        int n = n0 + ty + j * 8, k = k0 + tx;
        if (n < N && k < K) {
            const float x = tile[tx][ty + j * 8];
            const unsigned short h = f2b(x);
            hi_o[(long)n * K + k] = h;
            lo_o[(long)n * K + k] = f2b(x - b2f(h));
        }
    }
}

__global__ void convert_bf16(const float* __restrict__ in, unsigned short* __restrict__ out, int n4)
{
    int i = blockIdx.x * 256 + threadIdx.x;
    if (i < n4) {
        float4 v = ((const float4*)in)[i];
        ushort4 u;
        u.x = f2b(v.x); u.y = f2b(v.y); u.z = f2b(v.z); u.w = f2b(v.w);
        ((ushort4*)out)[i] = u;
    }
}

__global__ void gather_convert(const float* __restrict__ emb, const int* __restrict__ w,
                               unsigned short* __restrict__ out)
{
    const int r = blockIdx.x;
    const long row = w[r];
    const float4 v = ((const float4*)(emb + row * 512))[threadIdx.x];
    ushort4 u;
    u.x = f2b(v.x); u.y = f2b(v.y); u.z = f2b(v.z); u.w = f2b(v.w);
    ((ushort4*)(out + (long)r * 512))[threadIdx.x] = u;
}

// active-row compaction: ridx[i] = i-th (b,t) row with t < len[b]; *dcnt = count
__global__ void compact_rows(const int* __restrict__ len, int* __restrict__ ridx, int* __restrict__ dcnt)
{
    const int b = threadIdx.x;          // 64 threads
    int L = len[b]; L = L < 0 ? 0 : (L > Tn ? Tn : L);
    int off = L;
    #pragma unroll
    for (int s = 1; s < 64; s <<= 1) {
        int n = __shfl_up(off, s);
        if (b >= s) off += n;
    }
    const int start = off - L;
    if (b == 63) *dcnt = off;
    for (int t = 0; t < L; t++) ridx[start + t] = b * Tn + t;
}

__global__ void vg_mean(const unsigned short* __restrict__ vproj, float* __restrict__ vg)
{
    const int tid = blockIdx.x * 256 + threadIdx.x;
    const int b = tid >> 9, e = tid & 511;
    const unsigned short* p = vproj + (long)b * Pn * En + e;
    float s = 0.f;
    #pragma unroll 7
    for (int q = 0; q < Pn; q++) s += b2f(p[q * En]);
    vg[tid] = s * (1.0f / 49.0f);
}

// h0,m0; h0 -> hbF slot 0 (fp32 ping-pong buffer used by scan)
__global__ void h0m0(const float* __restrict__ vg,
                     const float* __restrict__ Wh, const float* __restrict__ bh,
                     const float* __restrict__ Wm, const float* __restrict__ bm,
                     float* __restrict__ h, float* __restrict__ m)
{
    __shared__ float vgs[512];
    const int b = blockIdx.x, e = threadIdx.x;
    vgs[e] = vg[b * 512 + e];
    __syncthreads();
    float a1 = bh[e], a2 = bm[e];
    #pragma unroll 8
    for (int k = 0; k < 512; k++) {
        const float x = vgs[k];
        a1 = fmaf(x, Wh[(long)k * 512 + e], a1);
        a2 = fmaf(x, Wm[(long)k * 512 + e], a2);
    }
    h[b * 512 + e] = a1;
    m[b * 512 + e] = a2;
}

// ---------------------------------------------------------------------------
// Persistent LSTM scan. 64 blocks x 256 threads, 1 block/CU (84KB LDS).
// Block owns e-slice [blk*8, blk*8+8) of h and the 5 matching gate columns of
// Wl3^T (split hi/lo bf16, resident in LDS). One grid barrier per step.
// gates = base[b*50+t] + h @ Wl3 (3-MFMA split-bf16 product, ~fp24 accurate).
// ---------------------------------------------------------------------------
__global__ __launch_bounds__(256)
void scan_kernel(const float* __restrict__ base,          // [3200][2560] (in d_out)
                 float* __restrict__ hbF,                 // [2][64*512] fp32 ping-pong
                 const float* __restrict__ m0,            // [64*512]
                 const unsigned short* __restrict__ W3h,  // [2560][512]
                 const unsigned short* __restrict__ W3l,
                 float* __restrict__ HsF,                 // [3200][512] fp32
                 unsigned short* __restrict__ Hsb,        // [3200][512] bf16
                 unsigned short* __restrict__ Ssb,
                 int* __restrict__ bar)                   // [2] zeroed each call
{
    __shared__ __align__(16) unsigned short Wh_s[5][8][520];
    __shared__ __align__(16) unsigned short Wl_s[5][8][520];
    __shared__ __align__(16) unsigned short zrow[520];

    const int tid = threadIdx.x;
    const int lane = tid & 63, wid = tid >> 6;
    const int blk = blockIdx.x;
    const int e0 = blk * 8;

    // stage the 40 weight rows (5 gates x 8 cols), FULL K=512: 64 segs of 8 bf16
    for (int idx = tid; idx < 40 * 64; idx += 256) {
        const int row = idx >> 6;          // (g,c) 0..39
        const int seg = idx & 63;          // 0..63
        const int g = row >> 3, c = row & 7;
        const long src = (long)(g * 512 + e0 + c) * 512 + seg * 8;
        *(uint4*)&Wh_s[g][c][seg * 8] = *(const uint4*)(W3h + src);
        *(uint4*)&Wl_s[g][c][seg * 8] = *(const uint4*)(W3l + src);
    }
    for (int idx = tid; idx < 520; idx += 256) zrow[idx] = 0;

    const int col = lane & 15;
    const bool active = col < 8;
    const int e = e0 + col;
    const int bbase = wid * 16 + (lane >> 4) * 4;
    float mreg[4];
    #pragma unroll
    for (int j = 0; j < 4; j++)
        mreg[j] = active ? m0[(bbase + j) * 512 + e] : 0.f;

    const int arow = wid * 16 + (lane & 15);
    const int kbase = (lane >> 4) * 8;

    __syncthreads();

    int gen = 0;
    for (int t = 0; t < Tn; t++) {
        const float* hb = hbF + (t & 1) * (64 * 512);
        float* hbn = hbF + ((t + 1) & 1) * (64 * 512);

        f32x4 acc[5] = {};
        const float* hrow = hb + arow * 512 + kbase;

        for (int kk = 0; kk < 512; kk += 32) {
            float hv[8];
            *(float4*)&hv[0] = *(const float4*)(hrow + kk);
            *(float4*)&hv[4] = *(const float4*)(hrow + kk + 4);
            bf16x8 ahi, alo;
            #pragma unroll
            for (int j = 0; j < 8; j++) {
                const unsigned short h = f2b(hv[j]);
                ahi[j] = (short)h;
                alo[j] = (short)f2b(hv[j] - b2f(h));
            }
            #pragma unroll
            for (int g = 0; g < 5; g++) {
                const bf16x8 bhi = *(const bf16x8*)(active ? &Wh_s[g][col][kk + kbase] : &zrow[kbase]);
                const bf16x8 blo = *(const bf16x8*)(active ? &Wl_s[g][col][kk + kbase] : &zrow[kbase]);
                acc[g] = __builtin_amdgcn_mfma_f32_16x16x32_bf16(ahi, bhi, acc[g], 0, 0, 0);
                acc[g] = __builtin_amdgcn_mfma_f32_16x16x32_bf16(alo, bhi, acc[g], 0, 0, 0);
                acc[g] = __builtin_amdgcn_mfma_f32_16x16x32_bf16(ahi, blo, acc[g], 0, 0, 0);
            }
        }

        if (active) {
            #pragma unroll
            for (int j = 0; j < 4; j++) {
                const int b = bbase + j;
                const long r = (long)b * Tn + t;
                const float* bs = base + r * G5;
                const float gi  = acc[0][j] + bs[e];
                const float gf  = acc[1][j] + bs[512 + e];
                const float go  = acc[2][j] + bs[1024 + e];
                const float gg  = acc[3][j] + bs[1536 + e];
                const float g5v = acc[4][j] + bs[2048 + e];
                const float iv = sigm(gi), fv = sigm(gf), ov = sigm(go);
                const float mn = fmaf(iv, tanh_f(g5v), fv * mreg[j]);
                const float tm = tanh_f(mn);
                const float hh = ov * tm, ss = gg * tm;
                mreg[j] = mn;
                hbn[b * 512 + e] = hh;
                HsF[r * 512 + e] = hh;
                Hsb[r * 512 + e] = f2b(hh);
                Ssb[r * 512 + e] = f2b(ss);
            }
        }

        // ---- grid barrier (all 64 blocks co-resident) ----
        __syncthreads();
        if (tid == 0) {
            __threadfence();
            const int old = __hip_atomic_fetch_add(&bar[0], 1, __ATOMIC_ACQ_REL, __HIP_MEMORY_SCOPE_AGENT);
            if (old == NBLK - 1) {
                __hip_atomic_store(&bar[0], 0, __ATOMIC_RELAXED, __HIP_MEMORY_SCOPE_AGENT);
                __hip_atomic_fetch_add(&bar[1], 1, __ATOMIC_RELEASE, __HIP_MEMORY_SCOPE_AGENT);
            } else {
                while (__hip_atomic_load(&bar[1], __ATOMIC_ACQUIRE, __HIP_MEMORY_SCOPE_AGENT) <= gen) {
                    __builtin_amdgcn_s_sleep(2);
                }
            }
            __threadfence();
        }
        gen++;
        __syncthreads();
    }
}

// Per-(b,t) adaptive attention; early-exit masked rows.
__global__ __launch_bounds__(256)
void attn(const unsigned short* __restrict__ vproj, const float* __restrict__ pv,
          const float* __restrict__ PH, const float* __restrict__ PS,
          const float* __restrict__ Hs, const float* __restrict__ Waz,
          const float* __restrict__ baz, unsigned short* __restrict__ CHb,
          const int* __restrict__ len)
{
    const int r = blockIdx.x;
    const int b = r / Tn;
    if ((r % Tn) >= len[b]) return;
    const int tid = threadIdx.x;
    const int lane = tid & 63, wid = tid >> 6;

    __shared__ float ps_s[512];
    __shared__ float ph_s[512];
    __shared__ float alog[64];

    for (int i = tid; i < 512; i += 256) {
        ps_s[i] = PS[(long)r * 512 + i];
        ph_s[i] = PH[(long)r * 512 + i];
    }
    __syncthreads();

    const float4 wz0 = *(const float4*)(Waz + lane * 8);
    const float4 wz1 = *(const float4*)(Waz + lane * 8 + 4);
    const float4 q0  = *(const float4*)&ps_s[lane * 8];
    const float4 q1  = *(const float4*)&ps_s[lane * 8 + 4];

    for (int slot = wid; slot < Pn + 1; slot += 4) {
        const float* src = (slot < Pn) ? (pv + ((long)b * Pn + slot) * 512)
                                       : (const float*)ph_s;
        const float4 x0 = *(const float4*)(src + lane * 8);
        const float4 x1 = *(const float4*)(src + lane * 8 + 4);
        float d = 0.f;
        d = fmaf(tanh_f(x0.x + q0.x), wz0.x, d);
        d = fmaf(tanh_f(x0.y + q0.y), wz0.y, d);
        d = fmaf(tanh_f(x0.z + q0.z), wz0.z, d);
        d = fmaf(tanh_f(x0.w + q0.w), wz0.w, d);
        d = fmaf(tanh_f(x1.x + q1.x), wz1.x, d);
        d = fmaf(tanh_f(x1.y + q1.y), wz1.y, d);
        d = fmaf(tanh_f(x1.z + q1.z), wz1.z, d);
        d = fmaf(tanh_f(x1.w + q1.w), wz1.w, d);
        #pragma unroll
        for (int s = 32; s >= 1; s >>= 1) d += __shfl_xor(d, s);
        if (lane == 0) alog[slot] = d + baz[0];
    }
    __syncthreads();

    if (wid == 0) {
        const float v = (lane < Pn + 1) ? alog[lane] : -3.4e38f;
        float mx = v;
        #pragma unroll
        for (int s = 32; s >= 1; s >>= 1) mx = fmaxf(mx, __shfl_xor(mx, s));
        const float ev = (lane < Pn + 1) ? __expf(v - mx) : 0.f;
        float sm = ev;
        #pragma unroll
        for (int s = 32; s >= 1; s >>= 1) sm += __shfl_xor(sm, s);
        if (lane < Pn + 1) alog[lane] = ev / sm;
    }
    __syncthreads();

    const float a49 = alog[Pn];
    for (int ee = tid; ee < 512; ee += 256) {
        const float hval = Hs[(long)r * 512 + ee];
        float c = a49 * hval;
        const unsigned short* vp = vproj + (long)b * Pn * 512 + ee;
        #pragma unroll 7
        for (int q = 0; q < Pn; q++) c = fmaf(alog[q], b2f(vp[q * 512]), c);
        CHb[(long)r * 512 + ee] = f2b(c + hval);
    }
}

__global__ __launch_bounds__(256)
void softmax_mask(float* __restrict__ out, const int* __restrict__ lengths)
{
    const int r = blockIdx.x, b = r / Tn, t = r % Tn;
    float* row = out + (long)r * Vn;
    const int tid = threadIdx.x;
    float4* row4 = (float4*)row;

    if (t >= lengths[b]) {
        const float4 z = {0.f, 0.f, 0.f, 0.f};
        for (int i = tid; i < Vn / 4; i += 256) row4[i] = z;
        return;
    }

    __shared__ float red[4];
    const int lane = tid & 63, wid = tid >> 6;

    float mx = -3.4e38f;
    for (int i = tid; i < Vn / 4; i += 256) {
        const float4 v = row4[i];
        mx = fmaxf(mx, fmaxf(fmaxf(v.x, v.y), fmaxf(v.z, v.w)));
    }
    #pragma unroll
    for (int s = 32; s >= 1; s >>= 1) mx = fmaxf(mx, __shfl_xor(mx, s));
    if (lane == 0) red[wid] = mx;
    __syncthreads();
    mx = fmaxf(fmaxf(red[0], red[1]), fmaxf(red[2], red[3]));

    float sm = 0.f;
    for (int i = tid; i < Vn / 4; i += 256) {
        const float4 v = row4[i];
        sm += __expf(v.x - mx) + __expf(v.y - mx) + __expf(v.z - mx) + __expf(v.w - mx);
    }
    #pragma unroll
    for (int s = 32; s >= 1; s >>= 1) sm += __shfl_xor(sm, s);
    __syncthreads();
    if (lane == 0) red[wid] = sm;
    __syncthreads();
    sm = red[0] + red[1] + red[2] + red[3];
    const float inv = 1.0f / sm;

    for (int i = tid; i < Vn / 4; i += 256) {
        float4 v = row4[i];
        v.x = __expf(v.x - mx) * inv;
        v.y = __expf(v.y - mx) * inv;
        v.z = __expf(v.z - mx) * inv;
        v.w = __expf(v.w - mx) * inv;
        row4[i] = v;
    }
}

extern "C" void kernel_launch(void* const* d_in, const int* in_sizes, int n_in,
                              void* d_out, int out_size, void* d_ws, size_t ws_size,
                              hipStream_t stream)
{
    (void)in_sizes; (void)n_in; (void)out_size; (void)ws_size;
    const float* v   = (const float*)d_in[0];
    const int*   w   = (const int*)  d_in[1];
    const int*   len = (const int*)  d_in[2];
    const float* emb = (const float*)d_in[3];
    const float* Wv  = (const float*)d_in[4];
    const float* bv  = (const float*)d_in[5];
    const float* Wh  = (const float*)d_in[6];
    const float* bh  = (const float*)d_in[7];
    const float* Wm  = (const float*)d_in[8];
    const float* bm  = (const float*)d_in[9];
    const float* Wl  = (const float*)d_in[10];
    const float* bl  = (const float*)d_in[11];
    const float* Wav = (const float*)d_in[12];
    const float* bav = (const float*)d_in[13];
    const float* Wah = (const float*)d_in[14];
    const float* bah = (const float*)d_in[15];
    const float* Was = (const float*)d_in[16];
    const float* bas = (const float*)d_in[17];
    const float* Waz = (const float*)d_in[18];
    const float* baz = (const float*)d_in[19];
    const float* Wp  = (const float*)d_in[20];
    const float* bp  = (const float*)d_in[21];
    float* out_f = (float*)d_out;

    // ---- workspace carve (~23 MB) ----
    char* wsp = (char*)d_ws;
    size_t off = 0;
    auto walloc = [&](size_t bytes) -> void* {
        void* r = wsp + off;
        off += (bytes + 255) & ~(size_t)255;
        return r;
    };
    unsigned short* WpT    = (unsigned short*)walloc((size_t)Vn * 512 * 2);
    unsigned short* WvT    = (unsigned short*)walloc((size_t)512 * 1024 * 2);
    unsigned short* WlT0   = (unsigned short*)walloc((size_t)G5 * 512 * 2);
    unsigned short* WavT   = (unsigned short*)walloc((size_t)512 * 512 * 2);
    unsigned short* WahT   = (unsigned short*)walloc((size_t)512 * 512 * 2);
    unsigned short* WasT   = (unsigned short*)walloc((size_t)512 * 512 * 2);
    unsigned short* vprojb = (unsigned short*)walloc((size_t)3136 * 512 * 2);
    unsigned short* CHb    = (unsigned short*)walloc((size_t)3200 * 512 * 2);
    float* vg   = (float*)walloc((size_t)64 * 512 * 4);
    float* hbF  = (float*)walloc((size_t)2 * 64 * 512 * 4);   // ping-pong h (fp32)
    float* mbuf = (float*)walloc((size_t)64 * 512 * 4);
    float* vgw  = (float*)walloc((size_t)64 * G5 * 4);
    int*   ridx = (int*)walloc((size_t)3200 * 4);
    int*   dcnt = (int*)walloc(256);
    int*   bar  = (int*)walloc(256);

    // ---- scratch in dead upper region of d_out (dead before logits GEMM) ----
    char* sp = (char*)(out_f + (size_t)3200 * G5);
    size_t off2 = 0;
    auto salloc = [&](size_t bytes) -> void* {
        void* r = sp + off2;
        off2 += (bytes + 255) & ~(size_t)255;
        return r;
    };
    unsigned short* vB  = (unsigned short*)salloc((size_t)3136 * 1024 * 2);
    unsigned short* WEb = (unsigned short*)salloc((size_t)3200 * 512 * 2);
    float* pvb = (float*)salloc((size_t)3136 * 512 * 4);
    float* HsF = (float*)salloc((size_t)3200 * 512 * 4);
    unsigned short* Hsb = (unsigned short*)salloc((size_t)3200 * 512 * 2);
    unsigned short* Ssb = (unsigned short*)salloc((size_t)3200 * 512 * 2);
    float* PHb = (float*)salloc((size_t)3200 * 512 * 4);
    float* PSb = (float*)salloc((size_t)3200 * 512 * 4);
    unsigned short* W3h = (unsigned short*)salloc((size_t)G5 * 512 * 2);
    unsigned short* W3l = (unsigned short*)salloc((size_t)G5 * 512 * 2);

    hipMemsetAsync(bar, 0, 16, stream);

    // ---- prep: transposes / conversions / compaction ----
    transpose_bf16<<<dim3(512/32, 1024/32), 256, 0, stream>>>(Wv, WvT, 1024, 512, 512);
    transpose_bf16<<<dim3(G5/32, 512/32), 256, 0, stream>>>(Wl, WlT0, 512, G5, G5);
    transpose_bf16<<<dim3(16, 16), 256, 0, stream>>>(Wav, WavT, 512, 512, 512);
    transpose_bf16<<<dim3(16, 16), 256, 0, stream>>>(Wah, WahT, 512, 512, 512);
    transpose_bf16<<<dim3(16, 16), 256, 0, stream>>>(Was, WasT, 512, 512, 512);
    transpose_bf16<<<dim3((Vn + 31)/32, 16), 256, 0, stream>>>(Wp, WpT, 512, Vn, Vn);
    transpose_bf16_hilo<<<dim3(G5/32, 16), 256, 0, stream>>>(Wl + (size_t)1024 * G5, W3h, W3l, 512, G5, G5);
    convert_bf16<<<(3136*1024/4 + 255)/256, 256, 0, stream>>>(v, vB, 3136*1024/4);
    gather_convert<<<3200, 128, 0, stream>>>(emb, w, WEb);
    compact_rows<<<1, 64, 0, stream>>>(len, ridx, dcnt);

    // 1. vproj(bf16) = v @ Wv + bv
    gemm_mfma<0,1,0><<<dim3(4, 25), 256, 0, stream>>>(vB, WvT, nullptr, vprojb,
                                                      3136, 512, 1024, bv, nullptr, 1, nullptr, nullptr);
    // 2-3. vg ; h0 (-> hbF slot0), m0
    vg_mean<<<128, 256, 0, stream>>>(vprojb, vg);
    h0m0<<<64, 512, 0, stream>>>(vg, Wh, bh, Wm, bm, hbF, mbuf);
    // 4. vgw = vg @ Wl[512:1024] + bl (fp32)
    gemm64<false><<<dim3(40, 1, 1), 256, 0, stream>>>(vg, 512, Wl + (size_t)512 * G5, vgw,
                                                      64, G5, 512, bl, nullptr, 1, 0, nullptr);
    // 5. pv = vproj @ Wav + bav
    gemm_mfma<1,0,0><<<dim3(4, 25), 256, 0, stream>>>(vprojb, WavT, pvb, nullptr,
                                                      3136, 512, 512, bav, nullptr, 1, nullptr, nullptr);
    // 6. base = we @ Wl[0:512] + vgw[b]  -> d_out rows (dead before logits)
    gemm_mfma<1,0,0><<<dim3(20, 25), 256, 0, stream>>>(WEb, WlT0, out_f, nullptr,
                                                       3200, G5, 512, nullptr, vgw, Tn, nullptr, nullptr);
    // 7. persistent 50-step scan (single dispatch)
    scan_kernel<<<NBLK, 256, 0, stream>>>(out_f, hbF, mbuf, W3h, W3l, HsF, Hsb, Ssb, bar);
    // 8. PH, PS
    gemm_mfma<1,0,0><<<dim3(4, 25), 256, 0, stream>>>(Hsb, WahT, PHb, nullptr,
                                                      3200, 512, 512, bah, nullptr, 1, nullptr, nullptr);
    gemm_mfma<1,0,0><<<dim3(4, 25), 256, 0, stream>>>(Ssb, WasT, PSb, nullptr,
                                                      3200, 512, 512, bas, nullptr, 1, nullptr, nullptr);
    // 9. attention -> CH (bf16), active rows only
    attn<<<3200, 256, 0, stream>>>(vprojb, pvb, PHb, PSb, HsF, Waz, baz, CHb, len);
    // 10. logits = CH @ Wp + bp -> d_out (compacted rows, scatter)
    gemm_mfma<1,0,1><<<dim3(79, 25), 256, 0, stream>>>(CHb, WpT, out_f, nullptr,
                                                       3200, Vn, 512, bp, nullptr, 1, ridx, dcnt);
    // 11. softmax + mask
    softmax_mask<<<3200, 256, 0, stream>>>(out_f, len);
}